// Round 15
// baseline (146.715 us; speedup 1.0000x reference)
//
#include <hip/hip_runtime.h>
#include <hip/hip_fp16.h>

#define HD 8
#define CD 16
#define DIM 128
#define NEG_SLOPE 0.2f

typedef __attribute__((ext_vector_type(8))) _Float16 f16x8;
typedef __attribute__((ext_vector_type(4))) float    f32x4;

static __device__ __forceinline__ float lrelu(float v){ return v > 0.f ? v : NEG_SLOPE*v; }

// ---------------- K0: W fp32 [k][c] -> Wt fp16 [c][k] (B^T layout for MFMA) ----------------
__global__ __launch_bounds__(256) void k_wprep(const float* __restrict__ W, __half* __restrict__ Wt){
  int idx = blockIdx.x*256 + threadIdx.x;      // 16384 elements
  if (idx < DIM*DIM){
    int k = idx >> 7, c = idx & 127;
    Wt[(size_t)c*DIM + k] = __float2half(W[idx]);
  }
}

// ---------------- K1: h = x @ W via MFMA fp16, + alpha epilogue ----------------
__global__ __launch_bounds__(256, 3) void k_gemm(const float* __restrict__ x,
    const __half* __restrict__ Wt, const float* __restrict__ a_src_g, const float* __restrict__ a_dst_g,
    __half* __restrict__ hout, float* __restrict__ as_o, float* __restrict__ ad_o, int N)
{
  __shared__ __half xs[64*136];                // pad 128->136: breaks LDS bank aliasing
  const int tid  = threadIdx.x;
  const int lane = tid & 63;
  const int wv   = tid >> 6;
  const long nbase = (long)blockIdx.x * 64;

  // stage x (fp32 global, coalesced) -> fp16 LDS
  #pragma unroll
  for (int it = 0; it < 8; ++it){
    int lin = it*1024 + tid*4;
    int row = lin >> 7, col = lin & 127;
    long node = nbase + row;
    float4 v = make_float4(0.f,0.f,0.f,0.f);
    if (node < N) v = *(const float4*)(x + node*DIM + col);
    __half2* dst = (__half2*)(xs + row*136 + col);
    dst[0] = __floats2half2_rn(v.x, v.y);
    dst[1] = __floats2half2_rn(v.z, v.w);
  }
  __syncthreads();

  const int lrow = lane & 15;
  const int g    = lane >> 4;

  f16x8 af[4];
  #pragma unroll
  for (int ks = 0; ks < 4; ++ks)
    af[ks] = *(const f16x8*)(xs + (wv*16 + lrow)*136 + ks*32 + g*8);

  f32x4 accs[8];
  #pragma unroll
  for (int t = 0; t < 8; ++t){
    f32x4 acc = {0.f,0.f,0.f,0.f};
    #pragma unroll
    for (int ks = 0; ks < 4; ++ks){
      f16x8 bf = *(const f16x8*)(Wt + (size_t)(t*16 + lrow)*DIM + ks*32 + g*8);
      acc = __builtin_amdgcn_mfma_f32_16x16x32_f16(af[ks], bf, acc, 0, 0, 0);
    }
    accs[t] = acc;
  }

  // D -> LDS as fp16 h (reuse xs; wave touches only its own 16 rows, no sync needed)
  #pragma unroll
  for (int t = 0; t < 8; ++t)
    #pragma unroll
    for (int i = 0; i < 4; ++i)
      xs[(wv*16 + g*4 + i)*136 + t*16 + lrow] = __float2half(accs[t][i]);
  __syncthreads();

  // phase 2a: coalesced h store (uint4 = 8 halves)
  #pragma unroll
  for (int j = 0; j < 4; ++j){
    int idx = j*256 + tid;                     // 1024 segments of 16B
    int row = idx >> 4, seg = idx & 15;
    long node = nbase + row;
    if (node < N){
      uint4 v = *(const uint4*)((const char*)xs + row*272 + seg*16);
      *(uint4*)(hout + node*DIM + seg*8) = v;
    }
  }
  // phase 2b: alpha dots from LDS h (head hd = col-tile)
  #pragma unroll
  for (int j = 0; j < 2; ++j){
    int idx = j*256 + tid;                     // 512 (node,head) pairs
    int row = idx >> 3, hd = idx & 7;
    long node = nbase + row;
    if (node < N){
      const __half* hp = xs + row*136 + hd*16;
      float ps = 0.f, pd = 0.f;
      #pragma unroll
      for (int cc = 0; cc < 16; ++cc){
        float hv = __half2float(hp[cc]);
        ps += hv * a_src_g[hd*16 + cc];
        pd += hv * a_dst_g[hd*16 + cc];
      }
      as_o[node*HD + hd] = ps;
      ad_o[node*HD + hd] = pd;
    }
  }
}

// ---------------- CSR build ----------------
__global__ void k_zero(int* __restrict__ p, int n){
  int i = blockIdx.x*256 + threadIdx.x;
  if (i < n) p[i] = 0;
}

// 4 edges/thread, block-strided (coalesced within each step): 4 independent
// load->atomic chains in flight per lane (r6 showed 2% VALUBusy = pure latency).
__global__ void k_count(const int* __restrict__ dst, int* __restrict__ cnt, int E){
  int t0 = blockIdx.x*1024 + threadIdx.x;
  #pragma unroll
  for (int i = 0; i < 4; ++i){
    int e = t0 + i*256;
    if (e < E) atomicAdd(&cnt[dst[e]], 1);
  }
}

__global__ __launch_bounds__(256) void k_scan1(const int* __restrict__ cnt, int* __restrict__ bsum,
                                               int chunk, int N){
  __shared__ int tmp[256];
  int t = threadIdx.x;
  int base = blockIdx.x * chunk;
  int i = base + t;
  int v = (t < chunk && i < N) ? cnt[i] : 0;
  tmp[t] = v; __syncthreads();
  for (int off = 128; off > 0; off >>= 1){
    if (t < off) tmp[t] += tmp[t+off];
    __syncthreads();
  }
  if (t == 0) bsum[blockIdx.x] = tmp[0];
}

__global__ __launch_bounds__(256) void k_scan2(int* __restrict__ bsum, int* __restrict__ row_ofs, int N){
  __shared__ int tmp[256];
  int t = threadIdx.x;
  int v = bsum[t];
  tmp[t] = v; __syncthreads();
  for (int off = 1; off < 256; off <<= 1){
    int u = (t >= off) ? tmp[t-off] : 0;
    __syncthreads();
    tmp[t] += u;
    __syncthreads();
  }
  bsum[t] = tmp[t] - v;            // exclusive
  if (t == 255) row_ofs[N] = tmp[255];
}

__global__ __launch_bounds__(256) void k_scan3(const int* __restrict__ cnt, const int* __restrict__ bsum,
                                               int* __restrict__ row_ofs, int* __restrict__ wpos,
                                               int chunk, int N){
  __shared__ int tmp[256];
  int t = threadIdx.x;
  int base = blockIdx.x * chunk;
  int i = base + t;
  int v = (t < chunk && i < N) ? cnt[i] : 0;
  tmp[t] = v; __syncthreads();
  for (int off = 1; off < 256; off <<= 1){
    int u = (t >= off) ? tmp[t-off] : 0;
    __syncthreads();
    tmp[t] += u;
    __syncthreads();
  }
  int excl = tmp[t] - v;
  int bbase = bsum[blockIdx.x];
  if (t < chunk && i < N){
    row_ofs[i] = bbase + excl;
    wpos[i]    = bbase + excl;
  }
}

// scatter edges into CSR order — 4 edges/thread for MLP on the atomic chain.
__global__ void k_scatter(const int* __restrict__ src, const int* __restrict__ dst,
                          int* __restrict__ wpos, int* __restrict__ csr_src, int E){
  int t0 = blockIdx.x*1024 + threadIdx.x;
  #pragma unroll
  for (int i = 0; i < 4; ++i){
    int e = t0 + i*256;
    if (e < E){
      int d = dst[e];
      int pos = atomicAdd(&wpos[d], 1);
      csr_src[pos] = src[e];
    }
  }
}

// ---------------- K4: weighted gather (fp16 h), COOPERATIVE weights ----------------
// 4 waves/block, one node per wave. Lane t: head hb=t>>3, slot sl=t&7, dims 2t..2t+1.
// Weight redundancy eliminated: lane (hb,sl) computes edges sl and sl+8 for head hb
// only (2 __expf/chunk instead of 16), weights distributed via __shfl (LDS pipe,
// off the VALU issue path that r12 counters showed 73% busy). Invalid slots emit
// w=0 at the source lane, so consumers need no select.
__global__ __launch_bounds__(256) void k_aggr(const __half* __restrict__ h,
    const float* __restrict__ as_, const float* __restrict__ ad_,
    const int* __restrict__ row_ofs, const int* __restrict__ csr_src,
    const float* __restrict__ bias, float* __restrict__ out, int N)
{
  const int n = blockIdx.x*4 + (threadIdx.x >> 6);
  if (n >= N) return;
  const int t  = threadIdx.x & 63;
  const int hb = t >> 3;
  const int sl = t & 7;
  const int off = t*2;

  const float ad_n = ad_[(size_t)n*HD + hb];
  const float w_self = __expf(lrelu(as_[(size_t)n*HD + hb] + ad_n));

  float sum = w_self;
  float2 hv = __half22float2(*(const __half2*)(h + (size_t)n*DIM + off));
  float2 acc; acc.x = w_self*hv.x; acc.y = w_self*hv.y;

  const int ofs = row_ofs[n];
  const int deg = row_ofs[n+1] - ofs;

  for (int jb = 0; jb < deg; jb += 16){
    const int c = deg - jb;               // valid slots this chunk (>=1)
    int s[16];
    #pragma unroll
    for (int q = 0; q < 16; ++q){
      int sq = csr_src[ofs + jb + q];     // padded: safe to over-read
      s[q] = (q < c) ? sq : n;
    }

    __half2 hq[16];                        // 16 independent gathers, 1 VGPR each
    #pragma unroll
    for (int q = 0; q < 16; ++q)
      hq[q] = *(const __half2*)(h + (size_t)s[q]*DIM + off);

    // this lane's 2 weights (its own head, edges sl and sl+8); 0 for invalid
    float v0 = __expf(lrelu(as_[(size_t)s[sl]*HD + hb] + ad_n));
    float v1 = __expf(lrelu(as_[(size_t)s[sl+8]*HD + hb] + ad_n));
    const float wv0 = (sl     < c) ? v0 : 0.f;
    const float wv1 = (sl + 8 < c) ? v1 : 0.f;

    #pragma unroll
    for (int q = 0; q < 8; ++q){
      float w0 = __shfl(wv0, hb*8 + q);   // weight(edge q, head hb)
      float2 hf = __half22float2(hq[q]);
      sum += w0; acc.x += w0*hf.x; acc.y += w0*hf.y;
    }
    #pragma unroll
    for (int q = 0; q < 8; ++q){
      float w1 = __shfl(wv1, hb*8 + q);   // weight(edge q+8, head hb)
      float2 hf = __half22float2(hq[8+q]);
      sum += w1; acc.x += w1*hf.x; acc.y += w1*hf.y;
    }
  }

  const float2 bv = *(const float2*)(bias + off);
  const float inv = 1.0f / (sum + 1e-16f);
  float2 o;
  o.x = acc.x*inv + bv.x;
  o.y = acc.y*inv + bv.y;
  *(float2*)(out + (size_t)n*DIM + off) = o;
}

extern "C" void kernel_launch(void* const* d_in, const int* in_sizes, int n_in,
                              void* d_out, int out_size, void* d_ws, size_t ws_size,
                              hipStream_t stream)
{
  const float* x     = (const float*)d_in[0];
  const int*   ei    = (const int*)  d_in[1];
  const float* W     = (const float*)d_in[2];
  const float* a_src = (const float*)d_in[3];
  const float* a_dst = (const float*)d_in[4];
  const float* bias  = (const float*)d_in[5];
  float* out = (float*)d_out;

  const int N = in_sizes[0] / DIM;
  const int E = in_sizes[1] / 2;
  const int* src = ei;
  const int* dst = ei + E;

  char* w = (char*)d_ws;
  __half* h    = (__half*)w; w += (size_t)N*DIM*2;
  __half* Wt   = (__half*)w; w += (size_t)DIM*DIM*2;
  float* as_   = (float*)w; w += (size_t)N*HD*4;
  float* ad_   = (float*)w; w += (size_t)N*HD*4;
  int* csr_src = (int*)w;   w += (size_t)(E+16)*4;     // +16 pad for chunk over-read
  int* cnt     = (int*)w;   w += (size_t)N*4;
  int* wpos    = (int*)w;   w += (size_t)N*4;
  int* bsum    = (int*)w;   w += 256*4;
  int* row_ofs = (int*)w;   w += (size_t)(N+1)*4;

  const int chunk = (N + 255) / 256;   // 196 for N=50000 (must be <=256)

  hipLaunchKernelGGL(k_wprep,   dim3(64),           dim3(256), 0, stream, W, Wt);
  hipLaunchKernelGGL(k_gemm,    dim3((N+63)/64),    dim3(256), 0, stream, x, Wt, a_src, a_dst, h, as_, ad_, N);
  hipLaunchKernelGGL(k_zero,    dim3((N+255)/256),  dim3(256), 0, stream, cnt, N);
  hipLaunchKernelGGL(k_count,   dim3((E+1023)/1024),dim3(256), 0, stream, dst, cnt, E);
  hipLaunchKernelGGL(k_scan1,   dim3(256),          dim3(256), 0, stream, cnt, bsum, chunk, N);
  hipLaunchKernelGGL(k_scan2,   dim3(1),            dim3(256), 0, stream, bsum, row_ofs, N);
  hipLaunchKernelGGL(k_scan3,   dim3(256),          dim3(256), 0, stream, cnt, bsum, row_ofs, wpos, chunk, N);
  hipLaunchKernelGGL(k_scatter, dim3((E+1023)/1024),dim3(256), 0, stream, src, dst, wpos, csr_src, E);
  hipLaunchKernelGGL(k_aggr,    dim3((N+3)/4),      dim3(256), 0, stream, h, as_, ad_, row_ofs, csr_src, bias, out, N);
}

// Round 16
// 135.839 us; speedup vs baseline: 1.0801x; 1.0801x over previous
//
#include <hip/hip_runtime.h>
#include <hip/hip_fp16.h>

#define HD 8
#define CD 16
#define DIM 128
#define NEG_SLOPE 0.2f
#define SCAT_SHIFT 12                       // 4096-node ranges -> ~213KB csr slice per pass

typedef __attribute__((ext_vector_type(8))) _Float16 f16x8;
typedef __attribute__((ext_vector_type(4))) float    f32x4;

static __device__ __forceinline__ float lrelu(float v){ return v > 0.f ? v : NEG_SLOPE*v; }

// ---------------- K0: W fp32 [k][c] -> Wt fp16 [c][k] (B^T layout for MFMA) ----------------
__global__ __launch_bounds__(256) void k_wprep(const float* __restrict__ W, __half* __restrict__ Wt){
  int idx = blockIdx.x*256 + threadIdx.x;      // 16384 elements
  if (idx < DIM*DIM){
    int k = idx >> 7, c = idx & 127;
    Wt[(size_t)c*DIM + k] = __float2half(W[idx]);
  }
}

// ---------------- K1: h = x @ W via MFMA fp16, + alpha epilogue ----------------
__global__ __launch_bounds__(256, 3) void k_gemm(const float* __restrict__ x,
    const __half* __restrict__ Wt, const float* __restrict__ a_src_g, const float* __restrict__ a_dst_g,
    __half* __restrict__ hout, float* __restrict__ as_o, float* __restrict__ ad_o, int N)
{
  __shared__ __half xs[64*136];                // pad 128->136: breaks LDS bank aliasing
  const int tid  = threadIdx.x;
  const int lane = tid & 63;
  const int wv   = tid >> 6;
  const long nbase = (long)blockIdx.x * 64;

  // stage x (fp32 global, coalesced) -> fp16 LDS
  #pragma unroll
  for (int it = 0; it < 8; ++it){
    int lin = it*1024 + tid*4;
    int row = lin >> 7, col = lin & 127;
    long node = nbase + row;
    float4 v = make_float4(0.f,0.f,0.f,0.f);
    if (node < N) v = *(const float4*)(x + node*DIM + col);
    __half2* dst = (__half2*)(xs + row*136 + col);
    dst[0] = __floats2half2_rn(v.x, v.y);
    dst[1] = __floats2half2_rn(v.z, v.w);
  }
  __syncthreads();

  const int lrow = lane & 15;
  const int g    = lane >> 4;

  f16x8 af[4];
  #pragma unroll
  for (int ks = 0; ks < 4; ++ks)
    af[ks] = *(const f16x8*)(xs + (wv*16 + lrow)*136 + ks*32 + g*8);

  f32x4 accs[8];
  #pragma unroll
  for (int t = 0; t < 8; ++t){
    f32x4 acc = {0.f,0.f,0.f,0.f};
    #pragma unroll
    for (int ks = 0; ks < 4; ++ks){
      f16x8 bf = *(const f16x8*)(Wt + (size_t)(t*16 + lrow)*DIM + ks*32 + g*8);
      acc = __builtin_amdgcn_mfma_f32_16x16x32_f16(af[ks], bf, acc, 0, 0, 0);
    }
    accs[t] = acc;
  }

  // D -> LDS as fp16 h (reuse xs; wave touches only its own 16 rows, no sync needed)
  #pragma unroll
  for (int t = 0; t < 8; ++t)
    #pragma unroll
    for (int i = 0; i < 4; ++i)
      xs[(wv*16 + g*4 + i)*136 + t*16 + lrow] = __float2half(accs[t][i]);
  __syncthreads();

  // phase 2a: coalesced h store (uint4 = 8 halves)
  #pragma unroll
  for (int j = 0; j < 4; ++j){
    int idx = j*256 + tid;                     // 1024 segments of 16B
    int row = idx >> 4, seg = idx & 15;
    long node = nbase + row;
    if (node < N){
      uint4 v = *(const uint4*)((const char*)xs + row*272 + seg*16);
      *(uint4*)(hout + node*DIM + seg*8) = v;
    }
  }
  // phase 2b: alpha dots from LDS h (head hd = col-tile)
  #pragma unroll
  for (int j = 0; j < 2; ++j){
    int idx = j*256 + tid;                     // 512 (node,head) pairs
    int row = idx >> 3, hd = idx & 7;
    long node = nbase + row;
    if (node < N){
      const __half* hp = xs + row*136 + hd*16;
      float ps = 0.f, pd = 0.f;
      #pragma unroll
      for (int cc = 0; cc < 16; ++cc){
        float hv = __half2float(hp[cc]);
        ps += hv * a_src_g[hd*16 + cc];
        pd += hv * a_dst_g[hd*16 + cc];
      }
      as_o[node*HD + hd] = ps;
      ad_o[node*HD + hd] = pd;
    }
  }
}

// ---------------- CSR build ----------------
__global__ void k_zero(int* __restrict__ p, int n){
  int i = blockIdx.x*256 + threadIdx.x;
  if (i < n) p[i] = 0;
}

// 1 edge/thread (r15 post-mortem: 4/thread shrank the grid 4x, occupancy 47->19%,
// and regressed — TLP beats ILP on this pure-latency kernel).
__global__ void k_count(const int* __restrict__ dst, int* __restrict__ cnt, int E){
  int e = blockIdx.x*256 + threadIdx.x;
  if (e < E) atomicAdd(&cnt[dst[e]], 1);
}

__global__ __launch_bounds__(256) void k_scan1(const int* __restrict__ cnt, int* __restrict__ bsum,
                                               int chunk, int N){
  __shared__ int tmp[256];
  int t = threadIdx.x;
  int base = blockIdx.x * chunk;
  int i = base + t;
  int v = (t < chunk && i < N) ? cnt[i] : 0;
  tmp[t] = v; __syncthreads();
  for (int off = 128; off > 0; off >>= 1){
    if (t < off) tmp[t] += tmp[t+off];
    __syncthreads();
  }
  if (t == 0) bsum[blockIdx.x] = tmp[0];
}

__global__ __launch_bounds__(256) void k_scan2(int* __restrict__ bsum, int* __restrict__ row_ofs, int N){
  __shared__ int tmp[256];
  int t = threadIdx.x;
  int v = bsum[t];
  tmp[t] = v; __syncthreads();
  for (int off = 1; off < 256; off <<= 1){
    int u = (t >= off) ? tmp[t-off] : 0;
    __syncthreads();
    tmp[t] += u;
    __syncthreads();
  }
  bsum[t] = tmp[t] - v;            // exclusive
  if (t == 255) row_ofs[N] = tmp[255];
}

__global__ __launch_bounds__(256) void k_scan3(const int* __restrict__ cnt, const int* __restrict__ bsum,
                                               int* __restrict__ row_ofs, int* __restrict__ wpos,
                                               int chunk, int N){
  __shared__ int tmp[256];
  int t = threadIdx.x;
  int base = blockIdx.x * chunk;
  int i = base + t;
  int v = (t < chunk && i < N) ? cnt[i] : 0;
  tmp[t] = v; __syncthreads();
  for (int off = 1; off < 256; off <<= 1){
    int u = (t >= off) ? tmp[t-off] : 0;
    __syncthreads();
    tmp[t] += u;
    __syncthreads();
  }
  int excl = tmp[t] - v;
  int bbase = bsum[blockIdx.x];
  if (t < chunk && i < N){
    row_ofs[i] = bbase + excl;
    wpos[i]    = bbase + excl;
  }
}

// ---------------- pass-partitioned scatter ----------------
// r15 counters: WRITE_SIZE 37.6 MB ~= E x 64B — each random 4B csr store wrote back a
// full line, no L2 coalescing (dst-random order). Partition by dst range: pass p touches
// only a ~213KB slice of csr_src, which stays L2-resident until all its entries land.
// dst/src are read ONCE into registers; the pass loop is VALU-trivial. The empty asm
// memory clobber stops the compiler collapsing the loop into single-shot (which would
// restore the random-write pattern; correctness would survive, locality wouldn't).
__global__ void k_scatter(const int* __restrict__ src, const int* __restrict__ dst,
                          int* __restrict__ wpos, int* __restrict__ csr_src, int E, int npass){
  int e = blockIdx.x*256 + threadIdx.x;
  if (e >= E) return;
  int d = dst[e];
  int s = src[e];
  int myp = d >> SCAT_SHIFT;
  for (int p = 0; p < npass; ++p){
    if (myp == p){
      int pos = atomicAdd(&wpos[d], 1);
      csr_src[pos] = s;
    }
    asm volatile("" ::: "memory");
  }
}

// ---------------- K4: weighted gather (fp16 h), COOPERATIVE weights ----------------
__global__ __launch_bounds__(256) void k_aggr(const __half* __restrict__ h,
    const float* __restrict__ as_, const float* __restrict__ ad_,
    const int* __restrict__ row_ofs, const int* __restrict__ csr_src,
    const float* __restrict__ bias, float* __restrict__ out, int N)
{
  const int n = blockIdx.x*4 + (threadIdx.x >> 6);
  if (n >= N) return;
  const int t  = threadIdx.x & 63;
  const int hb = t >> 3;
  const int sl = t & 7;
  const int off = t*2;

  const float ad_n = ad_[(size_t)n*HD + hb];
  const float w_self = __expf(lrelu(as_[(size_t)n*HD + hb] + ad_n));

  float sum = w_self;
  float2 hv = __half22float2(*(const __half2*)(h + (size_t)n*DIM + off));
  float2 acc; acc.x = w_self*hv.x; acc.y = w_self*hv.y;

  const int ofs = row_ofs[n];
  const int deg = row_ofs[n+1] - ofs;

  for (int jb = 0; jb < deg; jb += 16){
    const int c = deg - jb;               // valid slots this chunk (>=1)
    int s[16];
    #pragma unroll
    for (int q = 0; q < 16; ++q){
      int sq = csr_src[ofs + jb + q];     // padded: safe to over-read
      s[q] = (q < c) ? sq : n;
    }

    __half2 hq[16];                        // 16 independent gathers, 1 VGPR each
    #pragma unroll
    for (int q = 0; q < 16; ++q)
      hq[q] = *(const __half2*)(h + (size_t)s[q]*DIM + off);

    // this lane's 2 weights (its own head, edges sl and sl+8); 0 for invalid
    float v0 = __expf(lrelu(as_[(size_t)s[sl]*HD + hb] + ad_n));
    float v1 = __expf(lrelu(as_[(size_t)s[sl+8]*HD + hb] + ad_n));
    const float wv0 = (sl     < c) ? v0 : 0.f;
    const float wv1 = (sl + 8 < c) ? v1 : 0.f;

    #pragma unroll
    for (int q = 0; q < 8; ++q){
      float w0 = __shfl(wv0, hb*8 + q);   // weight(edge q, head hb)
      float2 hf = __half22float2(hq[q]);
      sum += w0; acc.x += w0*hf.x; acc.y += w0*hf.y;
    }
    #pragma unroll
    for (int q = 0; q < 8; ++q){
      float w1 = __shfl(wv1, hb*8 + q);   // weight(edge q+8, head hb)
      float2 hf = __half22float2(hq[8+q]);
      sum += w1; acc.x += w1*hf.x; acc.y += w1*hf.y;
    }
  }

  const float2 bv = *(const float2*)(bias + off);
  const float inv = 1.0f / (sum + 1e-16f);
  float2 o;
  o.x = acc.x*inv + bv.x;
  o.y = acc.y*inv + bv.y;
  *(float2*)(out + (size_t)n*DIM + off) = o;
}

extern "C" void kernel_launch(void* const* d_in, const int* in_sizes, int n_in,
                              void* d_out, int out_size, void* d_ws, size_t ws_size,
                              hipStream_t stream)
{
  const float* x     = (const float*)d_in[0];
  const int*   ei    = (const int*)  d_in[1];
  const float* W     = (const float*)d_in[2];
  const float* a_src = (const float*)d_in[3];
  const float* a_dst = (const float*)d_in[4];
  const float* bias  = (const float*)d_in[5];
  float* out = (float*)d_out;

  const int N = in_sizes[0] / DIM;
  const int E = in_sizes[1] / 2;
  const int* src = ei;
  const int* dst = ei + E;

  char* w = (char*)d_ws;
  __half* h    = (__half*)w; w += (size_t)N*DIM*2;
  __half* Wt   = (__half*)w; w += (size_t)DIM*DIM*2;
  float* as_   = (float*)w; w += (size_t)N*HD*4;
  float* ad_   = (float*)w; w += (size_t)N*HD*4;
  int* csr_src = (int*)w;   w += (size_t)(E+16)*4;     // +16 pad for chunk over-read
  int* cnt     = (int*)w;   w += (size_t)N*4;
  int* wpos    = (int*)w;   w += (size_t)N*4;
  int* bsum    = (int*)w;   w += 256*4;
  int* row_ofs = (int*)w;   w += (size_t)(N+1)*4;

  const int chunk = (N + 255) / 256;   // 196 for N=50000 (must be <=256)
  const int npass = (N >> SCAT_SHIFT) + 1;   // 13 for N=50000

  hipLaunchKernelGGL(k_wprep,   dim3(64),          dim3(256), 0, stream, W, Wt);
  hipLaunchKernelGGL(k_gemm,    dim3((N+63)/64),   dim3(256), 0, stream, x, Wt, a_src, a_dst, h, as_, ad_, N);
  hipLaunchKernelGGL(k_zero,    dim3((N+255)/256), dim3(256), 0, stream, cnt, N);
  hipLaunchKernelGGL(k_count,   dim3((E+255)/256), dim3(256), 0, stream, dst, cnt, E);
  hipLaunchKernelGGL(k_scan1,   dim3(256),         dim3(256), 0, stream, cnt, bsum, chunk, N);
  hipLaunchKernelGGL(k_scan2,   dim3(1),           dim3(256), 0, stream, bsum, row_ofs, N);
  hipLaunchKernelGGL(k_scan3,   dim3(256),         dim3(256), 0, stream, cnt, bsum, row_ofs, wpos, chunk, N);
  hipLaunchKernelGGL(k_scatter, dim3((E+255)/256), dim3(256), 0, stream, src, dst, wpos, csr_src, E, npass);
  hipLaunchKernelGGL(k_aggr,    dim3((N+3)/4),     dim3(256), 0, stream, h, as_, ad_, row_ofs, csr_src, bias, out, N);
}

// Round 17
// 123.348 us; speedup vs baseline: 1.1894x; 1.1013x over previous
//
#include <hip/hip_runtime.h>
#include <hip/hip_fp16.h>

#define HD 8
#define CD 16
#define DIM 128
#define NEG_SLOPE 0.2f
#define SCAT_SHIFT 12                       // 4096-node ranges -> ~213KB csr slice per pass

typedef __attribute__((ext_vector_type(8))) _Float16 f16x8;
typedef __attribute__((ext_vector_type(4))) float    f32x4;

static __device__ __forceinline__ float lrelu(float v){ return v > 0.f ? v : NEG_SLOPE*v; }

// ---------------- K1: fused W-prep + cnt-zero (independent, block-partitioned) -------------
__global__ __launch_bounds__(256) void k_prep(const float* __restrict__ W, __half* __restrict__ Wt,
                                              int* __restrict__ cnt, int N){
  int b = blockIdx.x;
  if (b < 64){
    int idx = b*256 + threadIdx.x;           // 16384 elements of W
    int k = idx >> 7, c = idx & 127;
    Wt[(size_t)c*DIM + k] = __float2half(W[idx]);
  } else {
    int i = (b-64)*256 + threadIdx.x;
    if (i < N) cnt[i] = 0;
  }
}

// ---------------- K2: fused MFMA-gemm + edge-count (independent chains overlapped) ---------
// blocks [0,gb): h = x@W via MFMA fp16 + alpha epilogue (r10-verified layout).
// blocks [gb,..): k_count's 1-edge/thread atomics — previously serialized AFTER gemm on the
// stream despite touching disjoint data; fusing lets count's latency hide under gemm's MFMA.
__global__ __launch_bounds__(256, 3) void k_gc(const float* __restrict__ x,
    const __half* __restrict__ Wt, const float* __restrict__ a_src_g, const float* __restrict__ a_dst_g,
    __half* __restrict__ hout, float* __restrict__ as_o, float* __restrict__ ad_o, int N,
    const int* __restrict__ dst, int* __restrict__ cnt, int E, int gb)
{
  __shared__ __half xs[64*136];                // pad 128->136: breaks LDS bank aliasing
  const int b = blockIdx.x;

  if (b >= gb){                                // ---- count part ----
    int e = (b-gb)*256 + threadIdx.x;
    if (e < E) atomicAdd(&cnt[dst[e]], 1);
    return;
  }

  // ---- gemm part ----
  const int tid  = threadIdx.x;
  const int lane = tid & 63;
  const int wv   = tid >> 6;
  const long nbase = (long)b * 64;

  #pragma unroll
  for (int it = 0; it < 8; ++it){
    int lin = it*1024 + tid*4;
    int row = lin >> 7, col = lin & 127;
    long node = nbase + row;
    float4 v = make_float4(0.f,0.f,0.f,0.f);
    if (node < N) v = *(const float4*)(x + node*DIM + col);
    __half2* dstp = (__half2*)(xs + row*136 + col);
    dstp[0] = __floats2half2_rn(v.x, v.y);
    dstp[1] = __floats2half2_rn(v.z, v.w);
  }
  __syncthreads();

  const int lrow = lane & 15;
  const int g    = lane >> 4;

  f16x8 af[4];
  #pragma unroll
  for (int ks = 0; ks < 4; ++ks)
    af[ks] = *(const f16x8*)(xs + (wv*16 + lrow)*136 + ks*32 + g*8);

  f32x4 accs[8];
  #pragma unroll
  for (int t = 0; t < 8; ++t){
    f32x4 acc = {0.f,0.f,0.f,0.f};
    #pragma unroll
    for (int ks = 0; ks < 4; ++ks){
      f16x8 bf = *(const f16x8*)(Wt + (size_t)(t*16 + lrow)*DIM + ks*32 + g*8);
      acc = __builtin_amdgcn_mfma_f32_16x16x32_f16(af[ks], bf, acc, 0, 0, 0);
    }
    accs[t] = acc;
  }

  // D -> LDS as fp16 h (reuse xs; wave touches only its own 16 rows, no sync needed)
  #pragma unroll
  for (int t = 0; t < 8; ++t)
    #pragma unroll
    for (int i = 0; i < 4; ++i)
      xs[(wv*16 + g*4 + i)*136 + t*16 + lrow] = __float2half(accs[t][i]);
  __syncthreads();

  // phase 2a: coalesced h store (uint4 = 8 halves)
  #pragma unroll
  for (int j = 0; j < 4; ++j){
    int idx = j*256 + tid;                     // 1024 segments of 16B
    int row = idx >> 4, seg = idx & 15;
    long node = nbase + row;
    if (node < N){
      uint4 v = *(const uint4*)((const char*)xs + row*272 + seg*16);
      *(uint4*)(hout + node*DIM + seg*8) = v;
    }
  }
  // phase 2b: alpha dots from LDS h (head hd = col-tile)
  #pragma unroll
  for (int j = 0; j < 2; ++j){
    int idx = j*256 + tid;                     // 512 (node,head) pairs
    int row = idx >> 3, hd = idx & 7;
    long node = nbase + row;
    if (node < N){
      const __half* hp = xs + row*136 + hd*16;
      float ps = 0.f, pd = 0.f;
      #pragma unroll
      for (int cc = 0; cc < 16; ++cc){
        float hv = __half2float(hp[cc]);
        ps += hv * a_src_g[hd*16 + cc];
        pd += hv * a_dst_g[hd*16 + cc];
      }
      as_o[node*HD + hd] = ps;
      ad_o[node*HD + hd] = pd;
    }
  }
}

// ---------------- CSR scans ----------------
__global__ __launch_bounds__(256) void k_scan1(const int* __restrict__ cnt, int* __restrict__ bsum,
                                               int chunk, int N){
  __shared__ int tmp[256];
  int t = threadIdx.x;
  int base = blockIdx.x * chunk;
  int i = base + t;
  int v = (t < chunk && i < N) ? cnt[i] : 0;
  tmp[t] = v; __syncthreads();
  for (int off = 128; off > 0; off >>= 1){
    if (t < off) tmp[t] += tmp[t+off];
    __syncthreads();
  }
  if (t == 0) bsum[blockIdx.x] = tmp[0];
}

__global__ __launch_bounds__(256) void k_scan2(int* __restrict__ bsum, int* __restrict__ row_ofs, int N){
  __shared__ int tmp[256];
  int t = threadIdx.x;
  int v = bsum[t];
  tmp[t] = v; __syncthreads();
  for (int off = 1; off < 256; off <<= 1){
    int u = (t >= off) ? tmp[t-off] : 0;
    __syncthreads();
    tmp[t] += u;
    __syncthreads();
  }
  bsum[t] = tmp[t] - v;            // exclusive
  if (t == 255) row_ofs[N] = tmp[255];
}

__global__ __launch_bounds__(256) void k_scan3(const int* __restrict__ cnt, const int* __restrict__ bsum,
                                               int* __restrict__ row_ofs, int* __restrict__ wpos,
                                               int chunk, int N){
  __shared__ int tmp[256];
  int t = threadIdx.x;
  int base = blockIdx.x * chunk;
  int i = base + t;
  int v = (t < chunk && i < N) ? cnt[i] : 0;
  tmp[t] = v; __syncthreads();
  for (int off = 1; off < 256; off <<= 1){
    int u = (t >= off) ? tmp[t-off] : 0;
    __syncthreads();
    tmp[t] += u;
    __syncthreads();
  }
  int excl = tmp[t] - v;
  int bbase = bsum[blockIdx.x];
  if (t < chunk && i < N){
    row_ofs[i] = bbase + excl;
    wpos[i]    = bbase + excl;
  }
}

// ---------------- pass-partitioned scatter (r16-verified: kills 64B/edge write-amp) -------
__global__ void k_scatter(const int* __restrict__ src, const int* __restrict__ dst,
                          int* __restrict__ wpos, int* __restrict__ csr_src, int E, int npass){
  int e = blockIdx.x*256 + threadIdx.x;
  if (e >= E) return;
  int d = dst[e];
  int s = src[e];
  int myp = d >> SCAT_SHIFT;
  for (int p = 0; p < npass; ++p){
    if (myp == p){
      int pos = atomicAdd(&wpos[d], 1);
      csr_src[pos] = s;
    }
    asm volatile("" ::: "memory");
  }
}

// ---------------- K4: weighted gather (fp16 h), COOPERATIVE weights ----------------
__global__ __launch_bounds__(256) void k_aggr(const __half* __restrict__ h,
    const float* __restrict__ as_, const float* __restrict__ ad_,
    const int* __restrict__ row_ofs, const int* __restrict__ csr_src,
    const float* __restrict__ bias, float* __restrict__ out, int N)
{
  const int n = blockIdx.x*4 + (threadIdx.x >> 6);
  if (n >= N) return;
  const int t  = threadIdx.x & 63;
  const int hb = t >> 3;
  const int sl = t & 7;
  const int off = t*2;

  const float ad_n = ad_[(size_t)n*HD + hb];
  const float w_self = __expf(lrelu(as_[(size_t)n*HD + hb] + ad_n));

  float sum = w_self;
  float2 hv = __half22float2(*(const __half2*)(h + (size_t)n*DIM + off));
  float2 acc; acc.x = w_self*hv.x; acc.y = w_self*hv.y;

  const int ofs = row_ofs[n];
  const int deg = row_ofs[n+1] - ofs;

  for (int jb = 0; jb < deg; jb += 16){
    const int c = deg - jb;               // valid slots this chunk (>=1)
    int s[16];
    #pragma unroll
    for (int q = 0; q < 16; ++q){
      int sq = csr_src[ofs + jb + q];     // padded: safe to over-read
      s[q] = (q < c) ? sq : n;
    }

    __half2 hq[16];                        // 16 independent gathers, 1 VGPR each
    #pragma unroll
    for (int q = 0; q < 16; ++q)
      hq[q] = *(const __half2*)(h + (size_t)s[q]*DIM + off);

    // this lane's 2 weights (its own head, edges sl and sl+8); 0 for invalid
    float v0 = __expf(lrelu(as_[(size_t)s[sl]*HD + hb] + ad_n));
    float v1 = __expf(lrelu(as_[(size_t)s[sl+8]*HD + hb] + ad_n));
    const float wv0 = (sl     < c) ? v0 : 0.f;
    const float wv1 = (sl + 8 < c) ? v1 : 0.f;

    #pragma unroll
    for (int q = 0; q < 8; ++q){
      float w0 = __shfl(wv0, hb*8 + q);   // weight(edge q, head hb)
      float2 hf = __half22float2(hq[q]);
      sum += w0; acc.x += w0*hf.x; acc.y += w0*hf.y;
    }
    #pragma unroll
    for (int q = 0; q < 8; ++q){
      float w1 = __shfl(wv1, hb*8 + q);   // weight(edge q+8, head hb)
      float2 hf = __half22float2(hq[8+q]);
      sum += w1; acc.x += w1*hf.x; acc.y += w1*hf.y;
    }
  }

  const float2 bv = *(const float2*)(bias + off);
  const float inv = 1.0f / (sum + 1e-16f);
  float2 o;
  o.x = acc.x*inv + bv.x;
  o.y = acc.y*inv + bv.y;
  *(float2*)(out + (size_t)n*DIM + off) = o;
}

extern "C" void kernel_launch(void* const* d_in, const int* in_sizes, int n_in,
                              void* d_out, int out_size, void* d_ws, size_t ws_size,
                              hipStream_t stream)
{
  const float* x     = (const float*)d_in[0];
  const int*   ei    = (const int*)  d_in[1];
  const float* W     = (const float*)d_in[2];
  const float* a_src = (const float*)d_in[3];
  const float* a_dst = (const float*)d_in[4];
  const float* bias  = (const float*)d_in[5];
  float* out = (float*)d_out;

  const int N = in_sizes[0] / DIM;
  const int E = in_sizes[1] / 2;
  const int* src = ei;
  const int* dst = ei + E;

  char* w = (char*)d_ws;
  __half* h    = (__half*)w; w += (size_t)N*DIM*2;
  __half* Wt   = (__half*)w; w += (size_t)DIM*DIM*2;
  float* as_   = (float*)w; w += (size_t)N*HD*4;
  float* ad_   = (float*)w; w += (size_t)N*HD*4;
  int* csr_src = (int*)w;   w += (size_t)(E+16)*4;     // +16 pad for chunk over-read
  int* cnt     = (int*)w;   w += (size_t)N*4;
  int* wpos    = (int*)w;   w += (size_t)N*4;
  int* bsum    = (int*)w;   w += 256*4;
  int* row_ofs = (int*)w;   w += (size_t)(N+1)*4;

  const int chunk = (N + 255) / 256;        // 196 for N=50000 (must be <=256)
  const int npass = (N >> SCAT_SHIFT) + 1;  // 13 for N=50000
  const int gb    = (N + 63) / 64;          // 782 gemm blocks
  const int cb    = (E + 255) / 256;        // 2344 count blocks

  hipLaunchKernelGGL(k_prep,    dim3(64 + (N+255)/256), dim3(256), 0, stream, W, Wt, cnt, N);
  hipLaunchKernelGGL(k_gc,      dim3(gb + cb),          dim3(256), 0, stream,
                     x, Wt, a_src, a_dst, h, as_, ad_, N, dst, cnt, E, gb);
  hipLaunchKernelGGL(k_scan1,   dim3(256),              dim3(256), 0, stream, cnt, bsum, chunk, N);
  hipLaunchKernelGGL(k_scan2,   dim3(1),                dim3(256), 0, stream, bsum, row_ofs, N);
  hipLaunchKernelGGL(k_scan3,   dim3(256),              dim3(256), 0, stream, cnt, bsum, row_ofs, wpos, chunk, N);
  hipLaunchKernelGGL(k_scatter, dim3((E+255)/256),      dim3(256), 0, stream, src, dst, wpos, csr_src, E, npass);
  hipLaunchKernelGGL(k_aggr,    dim3((N+3)/4),          dim3(256), 0, stream, h, as_, ad_, row_ofs, csr_src, bias, out, N);
}

// Round 18
// 120.556 us; speedup vs baseline: 1.2170x; 1.0232x over previous
//
#include <hip/hip_runtime.h>
#include <hip/hip_fp16.h>

#define HD 8
#define CD 16
#define DIM 128
#define NEG_SLOPE 0.2f
#define SCAT_SHIFT 12                       // 4096-node ranges -> ~213KB csr slice per pass
#define NC 16                               // count-histogram copies (r17: 200ns/same-line atomic)

typedef __attribute__((ext_vector_type(8))) _Float16 f16x8;
typedef __attribute__((ext_vector_type(4))) float    f32x4;

static __device__ __forceinline__ float lrelu(float v){ return v > 0.f ? v : NEG_SLOPE*v; }

// ---------------- K1: fused W-prep + cnt-zero (independent, block-partitioned) -------------
__global__ __launch_bounds__(256) void k_prep(const float* __restrict__ W, __half* __restrict__ Wt,
                                              int* __restrict__ cnt, int Ntot){
  int b = blockIdx.x;
  if (b < 64){
    int idx = b*256 + threadIdx.x;           // 16384 elements of W
    int k = idx >> 7, c = idx & 127;
    Wt[(size_t)c*DIM + k] = __float2half(W[idx]);
  } else {
    int i = (b-64)*256 + threadIdx.x;        // zero all NC histogram copies
    if (i < Ntot) cnt[i] = 0;
  }
}

// ---------------- K2: fused MFMA-gemm + replicated edge-count ------------------------------
// blocks [0,gb): h = x@W via MFMA fp16 + alpha epilogue (r10-verified layout).
// blocks [gb,..): edge-count into histogram copy (blk&15) — r17 showed 43us at 4% VALUBusy:
// ~192 atomics per cnt line serialized at ~200ns each (memory-side RMW chain). 16 copies
// cut same-line chain depth to ~12; scan1/scan3 sum the copies.
__global__ __launch_bounds__(256, 3) void k_gc(const float* __restrict__ x,
    const __half* __restrict__ Wt, const float* __restrict__ a_src_g, const float* __restrict__ a_dst_g,
    __half* __restrict__ hout, float* __restrict__ as_o, float* __restrict__ ad_o, int N,
    const int* __restrict__ dst, int* __restrict__ cnt, int E, int gb)
{
  __shared__ __half xs[64*136];                // pad 128->136: breaks LDS bank aliasing
  const int b = blockIdx.x;

  if (b >= gb){                                // ---- count part ----
    int bb = b - gb;
    int e = bb*256 + threadIdx.x;
    if (e < E) atomicAdd(&cnt[(bb & (NC-1))*N + dst[e]], 1);
    return;
  }

  // ---- gemm part ----
  const int tid  = threadIdx.x;
  const int lane = tid & 63;
  const int wv   = tid >> 6;
  const long nbase = (long)b * 64;

  #pragma unroll
  for (int it = 0; it < 8; ++it){
    int lin = it*1024 + tid*4;
    int row = lin >> 7, col = lin & 127;
    long node = nbase + row;
    float4 v = make_float4(0.f,0.f,0.f,0.f);
    if (node < N) v = *(const float4*)(x + node*DIM + col);
    __half2* dstp = (__half2*)(xs + row*136 + col);
    dstp[0] = __floats2half2_rn(v.x, v.y);
    dstp[1] = __floats2half2_rn(v.z, v.w);
  }
  __syncthreads();

  const int lrow = lane & 15;
  const int g    = lane >> 4;

  f16x8 af[4];
  #pragma unroll
  for (int ks = 0; ks < 4; ++ks)
    af[ks] = *(const f16x8*)(xs + (wv*16 + lrow)*136 + ks*32 + g*8);

  f32x4 accs[8];
  #pragma unroll
  for (int t = 0; t < 8; ++t){
    f32x4 acc = {0.f,0.f,0.f,0.f};
    #pragma unroll
    for (int ks = 0; ks < 4; ++ks){
      f16x8 bf = *(const f16x8*)(Wt + (size_t)(t*16 + lrow)*DIM + ks*32 + g*8);
      acc = __builtin_amdgcn_mfma_f32_16x16x32_f16(af[ks], bf, acc, 0, 0, 0);
    }
    accs[t] = acc;
  }

  // D -> LDS as fp16 h (reuse xs; wave touches only its own 16 rows, no sync needed)
  #pragma unroll
  for (int t = 0; t < 8; ++t)
    #pragma unroll
    for (int i = 0; i < 4; ++i)
      xs[(wv*16 + g*4 + i)*136 + t*16 + lrow] = __float2half(accs[t][i]);
  __syncthreads();

  // phase 2a: coalesced h store (uint4 = 8 halves)
  #pragma unroll
  for (int j = 0; j < 4; ++j){
    int idx = j*256 + tid;                     // 1024 segments of 16B
    int row = idx >> 4, seg = idx & 15;
    long node = nbase + row;
    if (node < N){
      uint4 v = *(const uint4*)((const char*)xs + row*272 + seg*16);
      *(uint4*)(hout + node*DIM + seg*8) = v;
    }
  }
  // phase 2b: alpha dots from LDS h (head hd = col-tile)
  #pragma unroll
  for (int j = 0; j < 2; ++j){
    int idx = j*256 + tid;                     // 512 (node,head) pairs
    int row = idx >> 3, hd = idx & 7;
    long node = nbase + row;
    if (node < N){
      const __half* hp = xs + row*136 + hd*16;
      float ps = 0.f, pd = 0.f;
      #pragma unroll
      for (int cc = 0; cc < 16; ++cc){
        float hv = __half2float(hp[cc]);
        ps += hv * a_src_g[hd*16 + cc];
        pd += hv * a_dst_g[hd*16 + cc];
      }
      as_o[node*HD + hd] = ps;
      ad_o[node*HD + hd] = pd;
    }
  }
}

// ---------------- CSR scans (cnt = sum of NC histogram copies) ----------------
__global__ __launch_bounds__(256) void k_scan1(const int* __restrict__ cnt, int* __restrict__ bsum,
                                               int chunk, int N){
  __shared__ int tmp[256];
  int t = threadIdx.x;
  int base = blockIdx.x * chunk;
  int i = base + t;
  int v = 0;
  if (t < chunk && i < N){
    #pragma unroll
    for (int c = 0; c < NC; ++c) v += cnt[c*N + i];
  }
  tmp[t] = v; __syncthreads();
  for (int off = 128; off > 0; off >>= 1){
    if (t < off) tmp[t] += tmp[t+off];
    __syncthreads();
  }
  if (t == 0) bsum[blockIdx.x] = tmp[0];
}

__global__ __launch_bounds__(256) void k_scan2(int* __restrict__ bsum, int* __restrict__ row_ofs, int N){
  __shared__ int tmp[256];
  int t = threadIdx.x;
  int v = bsum[t];
  tmp[t] = v; __syncthreads();
  for (int off = 1; off < 256; off <<= 1){
    int u = (t >= off) ? tmp[t-off] : 0;
    __syncthreads();
    tmp[t] += u;
    __syncthreads();
  }
  bsum[t] = tmp[t] - v;            // exclusive
  if (t == 255) row_ofs[N] = tmp[255];
}

__global__ __launch_bounds__(256) void k_scan3(const int* __restrict__ cnt, const int* __restrict__ bsum,
                                               int* __restrict__ row_ofs, int* __restrict__ wpos,
                                               int chunk, int N){
  __shared__ int tmp[256];
  int t = threadIdx.x;
  int base = blockIdx.x * chunk;
  int i = base + t;
  int v = 0;
  if (t < chunk && i < N){
    #pragma unroll
    for (int c = 0; c < NC; ++c) v += cnt[c*N + i];
  }
  tmp[t] = v; __syncthreads();
  for (int off = 1; off < 256; off <<= 1){
    int u = (t >= off) ? tmp[t-off] : 0;
    __syncthreads();
    tmp[t] += u;
    __syncthreads();
  }
  int excl = tmp[t] - v;
  int bbase = bsum[blockIdx.x];
  if (t < chunk && i < N){
    row_ofs[i] = bbase + excl;
    wpos[i]    = bbase + excl;
  }
}

// ---------------- pass-partitioned scatter (r16-verified: kills 64B/edge write-amp) -------
__global__ void k_scatter(const int* __restrict__ src, const int* __restrict__ dst,
                          int* __restrict__ wpos, int* __restrict__ csr_src, int E, int npass){
  int e = blockIdx.x*256 + threadIdx.x;
  if (e >= E) return;
  int d = dst[e];
  int s = src[e];
  int myp = d >> SCAT_SHIFT;
  for (int p = 0; p < npass; ++p){
    if (myp == p){
      int pos = atomicAdd(&wpos[d], 1);
      csr_src[pos] = s;
    }
    asm volatile("" ::: "memory");
  }
}

// ---------------- K4: weighted gather (fp16 h), COOPERATIVE weights ----------------
__global__ __launch_bounds__(256) void k_aggr(const __half* __restrict__ h,
    const float* __restrict__ as_, const float* __restrict__ ad_,
    const int* __restrict__ row_ofs, const int* __restrict__ csr_src,
    const float* __restrict__ bias, float* __restrict__ out, int N)
{
  const int n = blockIdx.x*4 + (threadIdx.x >> 6);
  if (n >= N) return;
  const int t  = threadIdx.x & 63;
  const int hb = t >> 3;
  const int sl = t & 7;
  const int off = t*2;

  const float ad_n = ad_[(size_t)n*HD + hb];
  const float w_self = __expf(lrelu(as_[(size_t)n*HD + hb] + ad_n));

  float sum = w_self;
  float2 hv = __half22float2(*(const __half2*)(h + (size_t)n*DIM + off));
  float2 acc; acc.x = w_self*hv.x; acc.y = w_self*hv.y;

  const int ofs = row_ofs[n];
  const int deg = row_ofs[n+1] - ofs;

  for (int jb = 0; jb < deg; jb += 16){
    const int c = deg - jb;               // valid slots this chunk (>=1)
    int s[16];
    #pragma unroll
    for (int q = 0; q < 16; ++q){
      int sq = csr_src[ofs + jb + q];     // padded: safe to over-read
      s[q] = (q < c) ? sq : n;
    }

    __half2 hq[16];                        // 16 independent gathers, 1 VGPR each
    #pragma unroll
    for (int q = 0; q < 16; ++q)
      hq[q] = *(const __half2*)(h + (size_t)s[q]*DIM + off);

    // this lane's 2 weights (its own head, edges sl and sl+8); 0 for invalid
    float v0 = __expf(lrelu(as_[(size_t)s[sl]*HD + hb] + ad_n));
    float v1 = __expf(lrelu(as_[(size_t)s[sl+8]*HD + hb] + ad_n));
    const float wv0 = (sl     < c) ? v0 : 0.f;
    const float wv1 = (sl + 8 < c) ? v1 : 0.f;

    #pragma unroll
    for (int q = 0; q < 8; ++q){
      float w0 = __shfl(wv0, hb*8 + q);   // weight(edge q, head hb)
      float2 hf = __half22float2(hq[q]);
      sum += w0; acc.x += w0*hf.x; acc.y += w0*hf.y;
    }
    #pragma unroll
    for (int q = 0; q < 8; ++q){
      float w1 = __shfl(wv1, hb*8 + q);   // weight(edge q+8, head hb)
      float2 hf = __half22float2(hq[8+q]);
      sum += w1; acc.x += w1*hf.x; acc.y += w1*hf.y;
    }
  }

  const float2 bv = *(const float2*)(bias + off);
  const float inv = 1.0f / (sum + 1e-16f);
  float2 o;
  o.x = acc.x*inv + bv.x;
  o.y = acc.y*inv + bv.y;
  *(float2*)(out + (size_t)n*DIM + off) = o;
}

extern "C" void kernel_launch(void* const* d_in, const int* in_sizes, int n_in,
                              void* d_out, int out_size, void* d_ws, size_t ws_size,
                              hipStream_t stream)
{
  const float* x     = (const float*)d_in[0];
  const int*   ei    = (const int*)  d_in[1];
  const float* W     = (const float*)d_in[2];
  const float* a_src = (const float*)d_in[3];
  const float* a_dst = (const float*)d_in[4];
  const float* bias  = (const float*)d_in[5];
  float* out = (float*)d_out;

  const int N = in_sizes[0] / DIM;
  const int E = in_sizes[1] / 2;
  const int* src = ei;
  const int* dst = ei + E;

  char* w = (char*)d_ws;
  __half* h    = (__half*)w; w += (size_t)N*DIM*2;
  __half* Wt   = (__half*)w; w += (size_t)DIM*DIM*2;
  float* as_   = (float*)w; w += (size_t)N*HD*4;
  float* ad_   = (float*)w; w += (size_t)N*HD*4;
  int* csr_src = (int*)w;   w += (size_t)(E+16)*4;     // +16 pad for chunk over-read
  int* cnt     = (int*)w;   w += (size_t)NC*N*4;       // 16 histogram copies (3.2 MB)
  int* wpos    = (int*)w;   w += (size_t)N*4;
  int* bsum    = (int*)w;   w += 256*4;
  int* row_ofs = (int*)w;   w += (size_t)(N+1)*4;

  const int chunk = (N + 255) / 256;        // 196 for N=50000 (must be <=256)
  const int npass = (N >> SCAT_SHIFT) + 1;  // 13 for N=50000
  const int gb    = (N + 63) / 64;          // 782 gemm blocks
  const int cb    = (E + 255) / 256;        // 2344 count blocks
  const int Ntot  = NC * N;

  hipLaunchKernelGGL(k_prep,    dim3(64 + (Ntot+255)/256), dim3(256), 0, stream, W, Wt, cnt, Ntot);
  hipLaunchKernelGGL(k_gc,      dim3(gb + cb),             dim3(256), 0, stream,
                     x, Wt, a_src, a_dst, h, as_, ad_, N, dst, cnt, E, gb);
  hipLaunchKernelGGL(k_scan1,   dim3(256),                 dim3(256), 0, stream, cnt, bsum, chunk, N);
  hipLaunchKernelGGL(k_scan2,   dim3(1),                   dim3(256), 0, stream, bsum, row_ofs, N);
  hipLaunchKernelGGL(k_scan3,   dim3(256),                 dim3(256), 0, stream, cnt, bsum, row_ofs, wpos, chunk, N);
  hipLaunchKernelGGL(k_scatter, dim3((E+255)/256),         dim3(256), 0, stream, src, dst, wpos, csr_src, E, npass);
  hipLaunchKernelGGL(k_aggr,    dim3((N+3)/4),             dim3(256), 0, stream, h, as_, ad_, row_ofs, csr_src, bias, out, N);
}

// Round 20
// 96.723 us; speedup vs baseline: 1.5168x; 1.2464x over previous
//
#include <hip/hip_runtime.h>
#include <hip/hip_fp16.h>

#define HD 8
#define CD 16
#define DIM 128
#define NEG_SLOPE 0.2f
#define SCAT_SHIFT 12                       // 4096-node ranges -> ~213KB csr slice per pass

typedef __attribute__((ext_vector_type(8))) _Float16 f16x8;
typedef __attribute__((ext_vector_type(4))) float    f32x4;

static __device__ __forceinline__ float lrelu(float v){ return v > 0.f ? v : NEG_SLOPE*v; }

// ---------------- K1: fused W-prep + cnt-zero (independent, block-partitioned) -------------
__global__ __launch_bounds__(256) void k_prep(const float* __restrict__ W, __half* __restrict__ Wt,
                                              int* __restrict__ cnt, int N){
  int b = blockIdx.x;
  if (b < 64){
    int idx = b*256 + threadIdx.x;           // 16384 elements of W
    int k = idx >> 7, c = idx & 127;
    Wt[(size_t)c*DIM + k] = __float2half(W[idx]);
  } else {
    int i = (b-64)*256 + threadIdx.x;
    if (i < N) cnt[i] = 0;
  }
}

// ---------------- K2: fused MFMA-gemm + slot-recording edge-count --------------------------
// blocks [0,gb): h = x@W via MFMA fp16 + alpha epilogue (r10-verified layout).
// blocks [gb,..): count atomics ALSO record their return value as the edge's within-dst
// slot (coalesced 4B store) — this is the allocator, so k_scatter needs no atomic at all.
// r18 refuted chain-depth replication (16 copies: -2.7us) -> single cnt histogram.
__global__ __launch_bounds__(256, 3) void k_gc(const float* __restrict__ x,
    const __half* __restrict__ Wt, const float* __restrict__ a_src_g, const float* __restrict__ a_dst_g,
    __half* __restrict__ hout, float* __restrict__ as_o, float* __restrict__ ad_o, int N,
    const int* __restrict__ dst, int* __restrict__ cnt, int* __restrict__ slot, int E, int gb)
{
  __shared__ __half xs[64*136];                // pad 128->136: breaks LDS bank aliasing
  const int b = blockIdx.x;

  if (b >= gb){                                // ---- count + slot part ----
    int e = (b-gb)*256 + threadIdx.x;
    if (e < E) slot[e] = atomicAdd(&cnt[dst[e]], 1);
    return;
  }

  // ---- gemm part ----
  const int tid  = threadIdx.x;
  const int lane = tid & 63;
  const int wv   = tid >> 6;
  const long nbase = (long)b * 64;

  #pragma unroll
  for (int it = 0; it < 8; ++it){
    int lin = it*1024 + tid*4;
    int row = lin >> 7, col = lin & 127;
    long node = nbase + row;
    float4 v = make_float4(0.f,0.f,0.f,0.f);
    if (node < N) v = *(const float4*)(x + node*DIM + col);
    __half2* dstp = (__half2*)(xs + row*136 + col);
    dstp[0] = __floats2half2_rn(v.x, v.y);
    dstp[1] = __floats2half2_rn(v.z, v.w);
  }
  __syncthreads();

  const int lrow = lane & 15;
  const int g    = lane >> 4;

  f16x8 af[4];
  #pragma unroll
  for (int ks = 0; ks < 4; ++ks)
    af[ks] = *(const f16x8*)(xs + (wv*16 + lrow)*136 + ks*32 + g*8);

  f32x4 accs[8];
  #pragma unroll
  for (int t = 0; t < 8; ++t){
    f32x4 acc = {0.f,0.f,0.f,0.f};
    #pragma unroll
    for (int ks = 0; ks < 4; ++ks){
      f16x8 bf = *(const f16x8*)(Wt + (size_t)(t*16 + lrow)*DIM + ks*32 + g*8);
      acc = __builtin_amdgcn_mfma_f32_16x16x32_f16(af[ks], bf, acc, 0, 0, 0);
    }
    accs[t] = acc;
  }

  // D -> LDS as fp16 h (reuse xs; wave touches only its own 16 rows, no sync needed)
  #pragma unroll
  for (int t = 0; t < 8; ++t)
    #pragma unroll
    for (int i = 0; i < 4; ++i)
      xs[(wv*16 + g*4 + i)*136 + t*16 + lrow] = __float2half(accs[t][i]);
  __syncthreads();

  // phase 2a: coalesced h store (uint4 = 8 halves)
  #pragma unroll
  for (int j = 0; j < 4; ++j){
    int idx = j*256 + tid;                     // 1024 segments of 16B
    int row = idx >> 4, seg = idx & 15;
    long node = nbase + row;
    if (node < N){
      uint4 v = *(const uint4*)((const char*)xs + row*272 + seg*16);
      *(uint4*)(hout + node*DIM + seg*8) = v;
    }
  }
  // phase 2b: alpha dots from LDS h (head hd = col-tile)
  #pragma unroll
  for (int j = 0; j < 2; ++j){
    int idx = j*256 + tid;                     // 512 (node,head) pairs
    int row = idx >> 3, hd = idx & 7;
    long node = nbase + row;
    if (node < N){
      const __half* hp = xs + row*136 + hd*16;
      float ps = 0.f, pd = 0.f;
      #pragma unroll
      for (int cc = 0; cc < 16; ++cc){
        float hv = __half2float(hp[cc]);
        ps += hv * a_src_g[hd*16 + cc];
        pd += hv * a_dst_g[hd*16 + cc];
      }
      as_o[node*HD + hd] = ps;
      ad_o[node*HD + hd] = pd;
    }
  }
}

// ---------------- CSR scans (single histogram) ----------------
__global__ __launch_bounds__(256) void k_scan1(const int* __restrict__ cnt, int* __restrict__ bsum,
                                               int chunk, int N){
  __shared__ int tmp[256];
  int t = threadIdx.x;
  int base = blockIdx.x * chunk;
  int i = base + t;
  int v = (t < chunk && i < N) ? cnt[i] : 0;
  tmp[t] = v; __syncthreads();
  for (int off = 128; off > 0; off >>= 1){
    if (t < off) tmp[t] += tmp[t+off];
    __syncthreads();
  }
  if (t == 0) bsum[blockIdx.x] = tmp[0];
}

__global__ __launch_bounds__(256) void k_scan2(int* __restrict__ bsum, int* __restrict__ row_ofs, int N){
  __shared__ int tmp[256];
  int t = threadIdx.x;
  int v = bsum[t];
  tmp[t] = v; __syncthreads();
  for (int off = 1; off < 256; off <<= 1){
    int u = (t >= off) ? tmp[t-off] : 0;
    __syncthreads();
    tmp[t] += u;
    __syncthreads();
  }
  bsum[t] = tmp[t] - v;            // exclusive
  if (t == 255) row_ofs[N] = tmp[255];
}

__global__ __launch_bounds__(256) void k_scan3(const int* __restrict__ cnt, const int* __restrict__ bsum,
                                               int* __restrict__ row_ofs, int chunk, int N){
  __shared__ int tmp[256];
  int t = threadIdx.x;
  int base = blockIdx.x * chunk;
  int i = base + t;
  int v = (t < chunk && i < N) ? cnt[i] : 0;
  tmp[t] = v; __syncthreads();
  for (int off = 1; off < 256; off <<= 1){
    int u = (t >= off) ? tmp[t-off] : 0;
    __syncthreads();
    tmp[t] += u;
    __syncthreads();
  }
  int excl = tmp[t] - v;
  int bbase = bsum[blockIdx.x];
  if (t < chunk && i < N)
    row_ofs[i] = bbase + excl;
}

// ---------------- atomic-free pass-partitioned scatter ----------------
// pos = row_ofs[dst] + slot  (slot recorded by the count pass's atomic return value).
// Chain per edge is now load->load->store; pass partitioning (r16-verified) keeps the
// random csr_src stores L2-coalesced (~213KB slice per pass).
__global__ void k_scatter(const int* __restrict__ src, const int* __restrict__ dst,
                          const int* __restrict__ slot, const int* __restrict__ row_ofs,
                          int* __restrict__ csr_src, int E, int npass){
  int e = blockIdx.x*256 + threadIdx.x;
  if (e >= E) return;
  int d = dst[e];
  int s = src[e];
  int pos = row_ofs[d] + slot[e];          // row_ofs: 200KB, L2-resident random read
  int myp = d >> SCAT_SHIFT;
  for (int p = 0; p < npass; ++p){
    if (myp == p)
      csr_src[pos] = s;
    asm volatile("" ::: "memory");
  }
}

// ---------------- K4: weighted gather (fp16 h), COOPERATIVE weights ----------------
__global__ __launch_bounds__(256) void k_aggr(const __half* __restrict__ h,
    const float* __restrict__ as_, const float* __restrict__ ad_,
    const int* __restrict__ row_ofs, const int* __restrict__ csr_src,
    const float* __restrict__ bias, float* __restrict__ out, int N)
{
  const int n = blockIdx.x*4 + (threadIdx.x >> 6);
  if (n >= N) return;
  const int t  = threadIdx.x & 63;
  const int hb = t >> 3;
  const int sl = t & 7;
  const int off = t*2;

  const float ad_n = ad_[(size_t)n*HD + hb];
  const float w_self = __expf(lrelu(as_[(size_t)n*HD + hb] + ad_n));

  float sum = w_self;
  float2 hv = __half22float2(*(const __half2*)(h + (size_t)n*DIM + off));
  float2 acc; acc.x = w_self*hv.x; acc.y = w_self*hv.y;

  const int ofs = row_ofs[n];
  const int deg = row_ofs[n+1] - ofs;

  for (int jb = 0; jb < deg; jb += 16){
    const int c = deg - jb;               // valid slots this chunk (>=1)
    int s[16];
    #pragma unroll
    for (int q = 0; q < 16; ++q){
      int sq = csr_src[ofs + jb + q];     // padded: safe to over-read
      s[q] = (q < c) ? sq : n;
    }

    __half2 hq[16];                        // 16 independent gathers, 1 VGPR each
    #pragma unroll
    for (int q = 0; q < 16; ++q)
      hq[q] = *(const __half2*)(h + (size_t)s[q]*DIM + off);

    // this lane's 2 weights (its own head, edges sl and sl+8); 0 for invalid
    float v0 = __expf(lrelu(as_[(size_t)s[sl]*HD + hb] + ad_n));
    float v1 = __expf(lrelu(as_[(size_t)s[sl+8]*HD + hb] + ad_n));
    const float wv0 = (sl     < c) ? v0 : 0.f;
    const float wv1 = (sl + 8 < c) ? v1 : 0.f;

    #pragma unroll
    for (int q = 0; q < 8; ++q){
      float w0 = __shfl(wv0, hb*8 + q);   // weight(edge q, head hb)
      float2 hf = __half22float2(hq[q]);
      sum += w0; acc.x += w0*hf.x; acc.y += w0*hf.y;
    }
    #pragma unroll
    for (int q = 0; q < 8; ++q){
      float w1 = __shfl(wv1, hb*8 + q);   // weight(edge q+8, head hb)
      float2 hf = __half22float2(hq[8+q]);
      sum += w1; acc.x += w1*hf.x; acc.y += w1*hf.y;
    }
  }

  const float2 bv = *(const float2*)(bias + off);
  const float inv = 1.0f / (sum + 1e-16f);
  float2 o;
  o.x = acc.x*inv + bv.x;
  o.y = acc.y*inv + bv.y;
  *(float2*)(out + (size_t)n*DIM + off) = o;
}

extern "C" void kernel_launch(void* const* d_in, const int* in_sizes, int n_in,
                              void* d_out, int out_size, void* d_ws, size_t ws_size,
                              hipStream_t stream)
{
  const float* x     = (const float*)d_in[0];
  const int*   ei    = (const int*)  d_in[1];
  const float* W     = (const float*)d_in[2];
  const float* a_src = (const float*)d_in[3];
  const float* a_dst = (const float*)d_in[4];
  const float* bias  = (const float*)d_in[5];
  float* out = (float*)d_out;

  const int N = in_sizes[0] / DIM;
  const int E = in_sizes[1] / 2;
  const int* src = ei;
  const int* dst = ei + E;

  char* w = (char*)d_ws;
  __half* h    = (__half*)w; w += (size_t)N*DIM*2;
  __half* Wt   = (__half*)w; w += (size_t)DIM*DIM*2;
  float* as_   = (float*)w; w += (size_t)N*HD*4;
  float* ad_   = (float*)w; w += (size_t)N*HD*4;
  int* csr_src = (int*)w;   w += (size_t)(E+16)*4;     // +16 pad for chunk over-read
  int* slot    = (int*)w;   w += (size_t)E*4;          // within-dst slot per edge
  int* cnt     = (int*)w;   w += (size_t)N*4;
  int* bsum    = (int*)w;   w += 256*4;
  int* row_ofs = (int*)w;   w += (size_t)(N+1)*4;

  const int chunk = (N + 255) / 256;        // 196 for N=50000 (must be <=256)
  const int npass = (N >> SCAT_SHIFT) + 1;  // 13 for N=50000
  const int gb    = (N + 63) / 64;          // 782 gemm blocks
  const int cb    = (E + 255) / 256;        // 2344 count blocks

  hipLaunchKernelGGL(k_prep,    dim3(64 + (N+255)/256), dim3(256), 0, stream, W, Wt, cnt, N);
  hipLaunchKernelGGL(k_gc,      dim3(gb + cb),          dim3(256), 0, stream,
                     x, Wt, a_src, a_dst, h, as_, ad_, N, dst, cnt, slot, E, gb);
  hipLaunchKernelGGL(k_scan1,   dim3(256),              dim3(256), 0, stream, cnt, bsum, chunk, N);
  hipLaunchKernelGGL(k_scan2,   dim3(1),                dim3(256), 0, stream, bsum, row_ofs, N);
  hipLaunchKernelGGL(k_scan3,   dim3(256),              dim3(256), 0, stream, cnt, bsum, row_ofs, chunk, N);
  hipLaunchKernelGGL(k_scatter, dim3((E+255)/256),      dim3(256), 0, stream, src, dst, slot, row_ofs, csr_src, E, npass);
  hipLaunchKernelGGL(k_aggr,    dim3((N+3)/4),          dim3(256), 0, stream, h, as_, ad_, row_ofs, csr_src, bias, out, N);
}

// Round 21
// 96.506 us; speedup vs baseline: 1.5203x; 1.0023x over previous
//
#include <hip/hip_runtime.h>
#include <hip/hip_fp16.h>

#define HD 8
#define CD 16
#define DIM 128
#define NEG_SLOPE 0.2f
#define SCAT_SHIFT 12                       // 4096-node ranges -> ~213KB csr slice per pass
#define NX 8                                // per-XCD histogram copies

typedef __attribute__((ext_vector_type(8))) _Float16 f16x8;
typedef __attribute__((ext_vector_type(4))) float    f32x4;

static __device__ __forceinline__ float lrelu(float v){ return v > 0.f ? v : NEG_SLOPE*v; }

// ---------------- K1: fused W-prep + cnt-zero (independent, block-partitioned) -------------
__global__ __launch_bounds__(256) void k_prep(const float* __restrict__ W, __half* __restrict__ Wt,
                                              int* __restrict__ cnt8, int Ntot){
  int b = blockIdx.x;
  if (b < 64){
    int idx = b*256 + threadIdx.x;           // 16384 elements of W
    int k = idx >> 7, c = idx & 127;
    Wt[(size_t)c*DIM + k] = __float2half(W[idx]);
  } else {
    int i = (b-64)*256 + threadIdx.x;        // zero all NX histogram copies
    if (i < Ntot) cnt8[i] = 0;
  }
}

// ---------------- K2: fused MFMA-gemm + XCD-local slot-recording count ---------------------
// blocks [0,gb): h = x@W via MFMA fp16 + alpha epilogue (r10-verified layout).
// blocks [gb,..): count into the REAL XCD's private histogram copy with WORKGROUP-scope
// atomics (no sc1 -> RMW executes in local XCD L2, no fabric round-trip). r20 counters:
// agent-scope atomics wrote ~32B/op to the common point (WRITE_SIZE 36.6MB vs 18.6 accounted)
// — per-op fabric cost, address-independent (consistent with r18's replication null).
// slot packs (xcd<<8)|local_slot; scan3 expands per-copy offsets.
__global__ __launch_bounds__(256, 3) void k_gc(const float* __restrict__ x,
    const __half* __restrict__ Wt, const float* __restrict__ a_src_g, const float* __restrict__ a_dst_g,
    __half* __restrict__ hout, float* __restrict__ as_o, float* __restrict__ ad_o, int N,
    const int* __restrict__ dst, int* __restrict__ cnt8, int* __restrict__ slot, int E, int gb)
{
  __shared__ __half xs[64*136];                // pad 128->136: breaks LDS bank aliasing
  const int b = blockIdx.x;

  if (b >= gb){                                // ---- count + slot part ----
    int e = (b-gb)*256 + threadIdx.x;
    if (e < E){
      unsigned xcd;
      asm volatile("s_getreg_b32 %0, hwreg(HW_REG_XCC_ID)" : "=s"(xcd));
      xcd &= (NX-1);
      int d = dst[e];
      int ls = __hip_atomic_fetch_add(&cnt8[(size_t)xcd*N + d], 1,
                                      __ATOMIC_RELAXED, __HIP_MEMORY_SCOPE_WORKGROUP);
      slot[e] = (int)(xcd << 8) | ls;          // per-dst-per-XCD count << 256 (deg<=~40)
    }
    return;
  }

  // ---- gemm part ----
  const int tid  = threadIdx.x;
  const int lane = tid & 63;
  const int wv   = tid >> 6;
  const long nbase = (long)b * 64;

  #pragma unroll
  for (int it = 0; it < 8; ++it){
    int lin = it*1024 + tid*4;
    int row = lin >> 7, col = lin & 127;
    long node = nbase + row;
    float4 v = make_float4(0.f,0.f,0.f,0.f);
    if (node < N) v = *(const float4*)(x + node*DIM + col);
    __half2* dstp = (__half2*)(xs + row*136 + col);
    dstp[0] = __floats2half2_rn(v.x, v.y);
    dstp[1] = __floats2half2_rn(v.z, v.w);
  }
  __syncthreads();

  const int lrow = lane & 15;
  const int g    = lane >> 4;

  f16x8 af[4];
  #pragma unroll
  for (int ks = 0; ks < 4; ++ks)
    af[ks] = *(const f16x8*)(xs + (wv*16 + lrow)*136 + ks*32 + g*8);

  f32x4 accs[8];
  #pragma unroll
  for (int t = 0; t < 8; ++t){
    f32x4 acc = {0.f,0.f,0.f,0.f};
    #pragma unroll
    for (int ks = 0; ks < 4; ++ks){
      f16x8 bf = *(const f16x8*)(Wt + (size_t)(t*16 + lrow)*DIM + ks*32 + g*8);
      acc = __builtin_amdgcn_mfma_f32_16x16x32_f16(af[ks], bf, acc, 0, 0, 0);
    }
    accs[t] = acc;
  }

  // D -> LDS as fp16 h (reuse xs; wave touches only its own 16 rows, no sync needed)
  #pragma unroll
  for (int t = 0; t < 8; ++t)
    #pragma unroll
    for (int i = 0; i < 4; ++i)
      xs[(wv*16 + g*4 + i)*136 + t*16 + lrow] = __float2half(accs[t][i]);
  __syncthreads();

  // phase 2a: coalesced h store (uint4 = 8 halves)
  #pragma unroll
  for (int j = 0; j < 4; ++j){
    int idx = j*256 + tid;                     // 1024 segments of 16B
    int row = idx >> 4, seg = idx & 15;
    long node = nbase + row;
    if (node < N){
      uint4 v = *(const uint4*)((const char*)xs + row*272 + seg*16);
      *(uint4*)(hout + node*DIM + seg*8) = v;
    }
  }
  // phase 2b: alpha dots from LDS h (head hd = col-tile)
  #pragma unroll
  for (int j = 0; j < 2; ++j){
    int idx = j*256 + tid;                     // 512 (node,head) pairs
    int row = idx >> 3, hd = idx & 7;
    long node = nbase + row;
    if (node < N){
      const __half* hp = xs + row*136 + hd*16;
      float ps = 0.f, pd = 0.f;
      #pragma unroll
      for (int cc = 0; cc < 16; ++cc){
        float hv = __half2float(hp[cc]);
        ps += hv * a_src_g[hd*16 + cc];
        pd += hv * a_dst_g[hd*16 + cc];
      }
      as_o[node*HD + hd] = ps;
      ad_o[node*HD + hd] = pd;
    }
  }
}

// ---------------- CSR scans (sum of NX per-XCD copies) ----------------
__global__ __launch_bounds__(256) void k_scan1(const int* __restrict__ cnt8, int* __restrict__ bsum,
                                               int chunk, int N){
  __shared__ int tmp[256];
  int t = threadIdx.x;
  int base = blockIdx.x * chunk;
  int i = base + t;
  int v = 0;
  if (t < chunk && i < N){
    #pragma unroll
    for (int c = 0; c < NX; ++c) v += cnt8[(size_t)c*N + i];
  }
  tmp[t] = v; __syncthreads();
  for (int off = 128; off > 0; off >>= 1){
    if (t < off) tmp[t] += tmp[t+off];
    __syncthreads();
  }
  if (t == 0) bsum[blockIdx.x] = tmp[0];
}

__global__ __launch_bounds__(256) void k_scan2(int* __restrict__ bsum, int* __restrict__ row_ofs, int N){
  __shared__ int tmp[256];
  int t = threadIdx.x;
  int v = bsum[t];
  tmp[t] = v; __syncthreads();
  for (int off = 1; off < 256; off <<= 1){
    int u = (t >= off) ? tmp[t-off] : 0;
    __syncthreads();
    tmp[t] += u;
    __syncthreads();
  }
  bsum[t] = tmp[t] - v;            // exclusive
  if (t == 255) row_ofs[N] = tmp[255];
}

// scan3: row_ofs + per-XCD-copy exclusive offsets (cofs[i*NX+c])
__global__ __launch_bounds__(256) void k_scan3(const int* __restrict__ cnt8, const int* __restrict__ bsum,
                                               int* __restrict__ row_ofs, int* __restrict__ cofs,
                                               int chunk, int N){
  __shared__ int tmp[256];
  int t = threadIdx.x;
  int base = blockIdx.x * chunk;
  int i = base + t;
  int v[NX]; int tot = 0;
  if (t < chunk && i < N){
    #pragma unroll
    for (int c = 0; c < NX; ++c){ v[c] = cnt8[(size_t)c*N + i]; tot += v[c]; }
  }
  tmp[t] = tot; __syncthreads();
  for (int off = 1; off < 256; off <<= 1){
    int u = (t >= off) ? tmp[t-off] : 0;
    __syncthreads();
    tmp[t] += u;
    __syncthreads();
  }
  int excl = tmp[t] - tot;
  int bbase = bsum[blockIdx.x];
  if (t < chunk && i < N){
    int run = bbase + excl;
    row_ofs[i] = run;
    #pragma unroll
    for (int c = 0; c < NX; ++c){ cofs[(size_t)i*NX + c] = run; run += v[c]; }
  }
}

// ---------------- atomic-free pass-partitioned scatter ----------------
// pos = cofs[dst*NX + xcd] + local_slot (both recorded at count time).
__global__ void k_scatter(const int* __restrict__ src, const int* __restrict__ dst,
                          const int* __restrict__ slot, const int* __restrict__ cofs,
                          int* __restrict__ csr_src, int E, int npass){
  int e = blockIdx.x*256 + threadIdx.x;
  if (e >= E) return;
  int d = dst[e];
  int s = src[e];
  int sv = slot[e];
  int pos = cofs[(size_t)d*NX + (sv >> 8)] + (sv & 255);
  int myp = d >> SCAT_SHIFT;
  for (int p = 0; p < npass; ++p){
    if (myp == p)
      csr_src[pos] = s;
    asm volatile("" ::: "memory");
  }
}

// ---------------- K4: weighted gather (fp16 h), COOPERATIVE weights ----------------
__global__ __launch_bounds__(256) void k_aggr(const __half* __restrict__ h,
    const float* __restrict__ as_, const float* __restrict__ ad_,
    const int* __restrict__ row_ofs, const int* __restrict__ csr_src,
    const float* __restrict__ bias, float* __restrict__ out, int N)
{
  const int n = blockIdx.x*4 + (threadIdx.x >> 6);
  if (n >= N) return;
  const int t  = threadIdx.x & 63;
  const int hb = t >> 3;
  const int sl = t & 7;
  const int off = t*2;

  const float ad_n = ad_[(size_t)n*HD + hb];
  const float w_self = __expf(lrelu(as_[(size_t)n*HD + hb] + ad_n));

  float sum = w_self;
  float2 hv = __half22float2(*(const __half2*)(h + (size_t)n*DIM + off));
  float2 acc; acc.x = w_self*hv.x; acc.y = w_self*hv.y;

  const int ofs = row_ofs[n];
  const int deg = row_ofs[n+1] - ofs;

  for (int jb = 0; jb < deg; jb += 16){
    const int c = deg - jb;               // valid slots this chunk (>=1)
    int s[16];
    #pragma unroll
    for (int q = 0; q < 16; ++q){
      int sq = csr_src[ofs + jb + q];     // padded: safe to over-read
      s[q] = (q < c) ? sq : n;
    }

    __half2 hq[16];                        // 16 independent gathers, 1 VGPR each
    #pragma unroll
    for (int q = 0; q < 16; ++q)
      hq[q] = *(const __half2*)(h + (size_t)s[q]*DIM + off);

    // this lane's 2 weights (its own head, edges sl and sl+8); 0 for invalid
    float v0 = __expf(lrelu(as_[(size_t)s[sl]*HD + hb] + ad_n));
    float v1 = __expf(lrelu(as_[(size_t)s[sl+8]*HD + hb] + ad_n));
    const float wv0 = (sl     < c) ? v0 : 0.f;
    const float wv1 = (sl + 8 < c) ? v1 : 0.f;

    #pragma unroll
    for (int q = 0; q < 8; ++q){
      float w0 = __shfl(wv0, hb*8 + q);   // weight(edge q, head hb)
      float2 hf = __half22float2(hq[q]);
      sum += w0; acc.x += w0*hf.x; acc.y += w0*hf.y;
    }
    #pragma unroll
    for (int q = 0; q < 8; ++q){
      float w1 = __shfl(wv1, hb*8 + q);   // weight(edge q+8, head hb)
      float2 hf = __half22float2(hq[8+q]);
      sum += w1; acc.x += w1*hf.x; acc.y += w1*hf.y;
    }
  }

  const float2 bv = *(const float2*)(bias + off);
  const float inv = 1.0f / (sum + 1e-16f);
  float2 o;
  o.x = acc.x*inv + bv.x;
  o.y = acc.y*inv + bv.y;
  *(float2*)(out + (size_t)n*DIM + off) = o;
}

extern "C" void kernel_launch(void* const* d_in, const int* in_sizes, int n_in,
                              void* d_out, int out_size, void* d_ws, size_t ws_size,
                              hipStream_t stream)
{
  const float* x     = (const float*)d_in[0];
  const int*   ei    = (const int*)  d_in[1];
  const float* W     = (const float*)d_in[2];
  const float* a_src = (const float*)d_in[3];
  const float* a_dst = (const float*)d_in[4];
  const float* bias  = (const float*)d_in[5];
  float* out = (float*)d_out;

  const int N = in_sizes[0] / DIM;
  const int E = in_sizes[1] / 2;
  const int* src = ei;
  const int* dst = ei + E;

  char* w = (char*)d_ws;
  __half* h    = (__half*)w; w += (size_t)N*DIM*2;
  __half* Wt   = (__half*)w; w += (size_t)DIM*DIM*2;
  float* as_   = (float*)w; w += (size_t)N*HD*4;
  float* ad_   = (float*)w; w += (size_t)N*HD*4;
  int* csr_src = (int*)w;   w += (size_t)(E+16)*4;     // +16 pad for chunk over-read
  int* slot    = (int*)w;   w += (size_t)E*4;          // (xcd<<8)|local_slot per edge
  int* cnt8    = (int*)w;   w += (size_t)NX*N*4;       // per-XCD histogram copies (1.6 MB)
  int* cofs    = (int*)w;   w += (size_t)NX*N*4;       // per-(dst,xcd) exclusive offsets
  int* bsum    = (int*)w;   w += 256*4;
  int* row_ofs = (int*)w;   w += (size_t)(N+1)*4;

  const int chunk = (N + 255) / 256;        // 196 for N=50000 (must be <=256)
  const int npass = (N >> SCAT_SHIFT) + 1;  // 13 for N=50000
  const int gb    = (N + 63) / 64;          // 782 gemm blocks
  const int cb    = (E + 255) / 256;        // 2344 count blocks
  const int Ntot  = NX * N;

  hipLaunchKernelGGL(k_prep,    dim3(64 + (Ntot+255)/256), dim3(256), 0, stream, W, Wt, cnt8, Ntot);
  hipLaunchKernelGGL(k_gc,      dim3(gb + cb),             dim3(256), 0, stream,
                     x, Wt, a_src, a_dst, h, as_, ad_, N, dst, cnt8, slot, E, gb);
  hipLaunchKernelGGL(k_scan1,   dim3(256),                 dim3(256), 0, stream, cnt8, bsum, chunk, N);
  hipLaunchKernelGGL(k_scan2,   dim3(1),                   dim3(256), 0, stream, bsum, row_ofs, N);
  hipLaunchKernelGGL(k_scan3,   dim3(256),                 dim3(256), 0, stream, cnt8, bsum, row_ofs, cofs, chunk, N);
  hipLaunchKernelGGL(k_scatter, dim3((E+255)/256),         dim3(256), 0, stream, src, dst, slot, cofs, csr_src, E, npass);
  hipLaunchKernelGGL(k_aggr,    dim3((N+3)/4),             dim3(256), 0, stream, h, as_, ad_, row_ofs, csr_src, bias, out, N);
}